// Round 10
// baseline (258.405 us; speedup 1.0000x reference)
//
#include <hip/hip_runtime.h>
#include <cstdint>

#define NB1 8192
#define NB2 8192
#define DDIM 128
#define KROW 256           // stored row: [hi(128) | lo(128)] f16
#define NKITER 12          // virtual K = 384 (hi*hi + lo*hi + hi*lo), BK=32

using half8   = __attribute__((ext_vector_type(8))) _Float16;
using half4   = __attribute__((ext_vector_type(4))) _Float16;
using float4v = __attribute__((ext_vector_type(4))) float;

__device__ inline unsigned long long packkey(float v, int j) {
  unsigned u = __float_as_uint(v);
  u = (u & 0x80000000u) ? ~u : (u | 0x80000000u);  // monotone float->uint
  return ((unsigned long long)u << 32) | (unsigned)j;
}

// virtual kt -> source 32-f16 chunk index within the [hi|lo] row
__device__ __forceinline__ int a_src(int kt) { return (kt < 8) ? kt : kt - 8; } // hi,lo,hi
__device__ __forceinline__ int b_src(int kt) { return (kt < 4) ? kt : kt - 4; } // hi,hi,lo

// ---------------------------------------------------------------------------
// Kernel 0: fp32 -> f16 hi/lo split + squared norms + init packed keys.
// One wave per 2 rows; float4 loads, half4 stores.
// ---------------------------------------------------------------------------
__global__ __launch_bounds__(256) void convert_kernel(
    const float* __restrict__ d1, const float* __restrict__ d2,
    _Float16* __restrict__ A2, _Float16* __restrict__ B2,
    float* __restrict__ asq, float* __restrict__ bsq,
    unsigned long long* __restrict__ packed) {
  int gid  = blockIdx.x * 256 + threadIdx.x;
  int wv   = gid >> 6;
  int lane = gid & 63;
  int rowc = 2 * wv + (lane >> 5);
  bool isA = rowc < NB1;
  const float* src = isA ? d1 : d2;
  int row = isA ? rowc : rowc - NB1;
  int k4  = (lane & 31) * 4;

  float4 v = *(const float4*)&src[row * DDIM + k4];
  _Float16 h0 = (_Float16)v.x, h1 = (_Float16)v.y;
  _Float16 h2 = (_Float16)v.z, h3 = (_Float16)v.w;
  half4 hh = {h0, h1, h2, h3};
  half4 ll = {(_Float16)(v.x - (float)h0), (_Float16)(v.y - (float)h1),
              (_Float16)(v.z - (float)h2), (_Float16)(v.w - (float)h3)};

  _Float16* dst = (isA ? A2 : B2) + (size_t)row * KROW;
  *(half4*)&dst[k4]       = hh;
  *(half4*)&dst[128 + k4] = ll;

  float s = v.x * v.x + v.y * v.y + v.z * v.z + v.w * v.w;
  #pragma unroll
  for (int off = 16; off > 0; off >>= 1) s += __shfl_xor(s, off, 64);
  if ((lane & 31) == 0) (isA ? asq : bsq)[row] = s;

  if (gid < NB1) packed[gid] = 0xFFFFFFFFFFFFFFFFull;  // +inf key
}

// ---------------------------------------------------------------------------
// Kernel 1: barrier-free MFMA GEMM (virtual K=384 f16) + fused row argmin.
// 128x128 tile, 4 waves (2x2), 4x4 mfma_f32_16x16x32_f16 per wave.
// NO LDS staging: fragments load straight from global (L2-resident working
// set ~2 MB/XCD, proven by warm replays fetching 4 MB). The K-loop has ZERO
// barriers, so loads stay in flight across MFMAs (vmcnt(N), never a full
// drain) -- attacks the documented ~36%-MfmaUtil barrier-drain plateau.
// Wave-pairs sharing wm (A) / wn (B) re-read the same 4 KB per kt -> L1 hits.
// Explicit ping-pong (S0/S1 frag sets) pipelines one kt ahead.
// Epilogue: register fold -> pad-17 LDS lex-min -> atomicMin(packed).
// (Fused in-kernel output removed: R9 measured it at +12 us/dispatch.)
// ---------------------------------------------------------------------------
__global__ __launch_bounds__(256, 3) void mfma_match_kernel(
    const _Float16* __restrict__ A2, const _Float16* __restrict__ B2,
    const float* __restrict__ bsq, unsigned long long* __restrict__ packed) {
  __shared__ unsigned long long smem[2 * 128 * 17];  // epilogue reduce only

  const int t    = threadIdx.x;
  const int lane = t & 63;
  const int wid  = t >> 6;
  const int wm = wid >> 1, wn = wid & 1;
  const int lx = lane & 15, q = lane >> 4;

  // L2/XCD locality swizzle (dispatch round-robins id%8 across XCDs).
  const int id = blockIdx.x;
  const int xc = id & 7, kk = id >> 3;
  const int bx = ((kk >> 3) & 7) * 8 + xc;
  const int by = (kk & 7) + ((kk >> 6) & 7) * 8;
  const int row0 = bx * 128, col0 = by * 128;

  // Fragment base pointers: lane (lx,q) of wave (wm,wn) reads
  // A[row0 + wm*64 + 16r + lx][k = chunk*32 + q*8 .. +8) -- MFMA A-layout.
  const _Float16* Abase = A2 + (size_t)(row0 + wm * 64 + lx) * KROW + q * 8;
  const _Float16* Bbase = B2 + (size_t)(col0 + wn * 64 + lx) * KROW + q * 8;

  float4v acc[4][4];
  #pragma unroll
  for (int r = 0; r < 4; ++r)
    #pragma unroll
    for (int c = 0; c < 4; ++c) acc[r][c] = (float4v){0.f, 0.f, 0.f, 0.f};

  float bq[4]; int jc[4];
  #pragma unroll
  for (int c = 0; c < 4; ++c) {
    jc[c] = col0 + wn * 64 + 16 * c + lx;
    bq[c] = bsq[jc[c]];
  }

  half8 s0a[4], s0b[4], s1a[4], s1b[4];

  auto loadS = [&](half8* fa, half8* fb, int kt) {
    const int ka = a_src(kt) * 32, kb = b_src(kt) * 32;
    #pragma unroll
    for (int r = 0; r < 4; ++r)
      fa[r] = *(const half8*)(Abase + (size_t)(16 * r) * KROW + ka);
    #pragma unroll
    for (int c = 0; c < 4; ++c)
      fb[c] = *(const half8*)(Bbase + (size_t)(16 * c) * KROW + kb);
  };
  auto mfmaS = [&](const half8* fa, const half8* fb) {
    #pragma unroll
    for (int r = 0; r < 4; ++r)
      #pragma unroll
      for (int c = 0; c < 4; ++c)
        acc[r][c] = __builtin_amdgcn_mfma_f32_16x16x32_f16(
            fa[r], fb[c], acc[r][c], 0, 0, 0);
  };

  loadS(s0a, s0b, 0);
  #pragma unroll
  for (int kt2 = 0; kt2 < NKITER / 2; ++kt2) {
    loadS(s1a, s1b, 2 * kt2 + 1);   // prefetch odd kt while even computes
    mfmaS(s0a, s0b);
    if (kt2 < NKITER / 2 - 1) loadS(s0a, s0b, 2 * kt2 + 2);
    mfmaS(s1a, s1b);
  }

  // ---- Epilogue. C/D layout: col = lane&15, row = q*4 + reg. ----
  #pragma unroll
  for (int r = 0; r < 4; ++r) {
    #pragma unroll
    for (int reg = 0; reg < 4; ++reg) {
      float bv = 1e30f; int bj = 0;
      #pragma unroll
      for (int c = 0; c < 4; ++c) {  // jc ascending -> strict < keeps min j
        float val = fmaf(-2.f, acc[r][c][reg], bq[c]);
        if (val < bv) { bv = val; bj = jc[c]; }
      }
      int mrow = wm * 64 + 16 * r + 4 * q + reg;
      smem[(wn * 128 + mrow) * 17 + lx] = packkey(bv, bj);
    }
  }
  __syncthreads();
  if (t < 128) {
    unsigned long long best = ~0ull;
    #pragma unroll
    for (int w = 0; w < 2; ++w)
      #pragma unroll
      for (int x = 0; x < 16; ++x) {
        unsigned long long k = smem[(w * 128 + t) * 17 + x];
        if (k < best) best = k;
      }
    atomicMin(&packed[row0 + t], best);  // device-scope lex (val, idx) min
  }
}

// ---------------------------------------------------------------------------
// Kernel 2: decode packed keys, write outputs.
// ---------------------------------------------------------------------------
__global__ __launch_bounds__(256) void out_kernel(
    const unsigned long long* __restrict__ packed,
    const float* __restrict__ asq, float* __restrict__ out) {
  int r = blockIdx.x * 256 + threadIdx.x;
  unsigned long long best = packed[r];
  unsigned u = (unsigned)(best >> 32);
  u = (u & 0x80000000u) ? (u & 0x7fffffffu) : ~u;   // invert monotone map
  float dist = sqrtf(fmaxf(asq[r] + __uint_as_float(u), 0.f));
  int j = (int)(unsigned)(best & 0xffffffffu);
  out[r]               = dist;
  out[NB1 + 2 * r]     = (float)r;
  out[NB1 + 2 * r + 1] = (float)j;
}

extern "C" void kernel_launch(void* const* d_in, const int* in_sizes, int n_in,
                              void* d_out, int out_size, void* d_ws, size_t ws_size,
                              hipStream_t stream) {
  const float* d1 = (const float*)d_in[0];
  const float* d2 = (const float*)d_in[1];
  float* out = (float*)d_out;

  char* w = (char*)d_ws;
  float* asq = (float*)w;                                   // 32 KB
  float* bsq = (float*)(w + 32768);                         // 32 KB
  _Float16* A2 = (_Float16*)(w + 65536);                    // 4 MB
  _Float16* B2 = (_Float16*)(w + 65536 + 4194304);          // 4 MB
  unsigned long long* packed =
      (unsigned long long*)(w + 65536 + 2 * 4194304);       // 64 KB

  convert_kernel<<<(NB1 + NB2) / 8, 256, 0, stream>>>(
      d1, d2, A2, B2, asq, bsq, packed);

  mfma_match_kernel<<<(NB1 / 128) * (NB2 / 128), 256, 0, stream>>>(
      A2, B2, bsq, packed);

  out_kernel<<<NB1 / 256, 256, 0, stream>>>(packed, asq, out);
}